// Round 14
// baseline (265.985 us; speedup 1.0000x reference)
//
#include <hip/hip_runtime.h>
#include <cstddef>

#define NB 64
#define NP 1024
#define NPTS (NB * NP)

typedef __attribute__((ext_vector_type(8))) short v8s;
typedef __attribute__((ext_vector_type(4))) float f32x4;

__device__ __forceinline__ float dist2(const float4 pi, const float sqi, const float4 pq) {
    const float dot = fmaf(pi.z, pq.z, fmaf(pi.y, pq.y, pi.x * pq.x));
    return fmaf(-2.0f, dot, sqi + pq.w);
}

__device__ __forceinline__ void pack8(const float* w, v8s& hv, v8s& lv) {
    union { v8s v; unsigned int u[4]; } H, L;
#pragma unroll
    for (int p = 0; p < 4; ++p) {
        unsigned int a = __float_as_uint(w[2 * p]);
        unsigned int b = __float_as_uint(w[2 * p + 1]);
        unsigned int ha = a & 0xffff0000u, hb = b & 0xffff0000u;
        H.u[p] = (ha >> 16) | hb;
        float la = w[2 * p] - __uint_as_float(ha);
        float lb = w[2 * p + 1] - __uint_as_float(hb);
        L.u[p] = (__float_as_uint(la) >> 16) | (__float_as_uint(lb) & 0xffff0000u);
    }
    hv = H.v; lv = L.v;
}

// ---------------------------------------------------------------------------
// Kernel 1: top-6 kNN (R12 proven scan), launched as TWO half-grids (ofs =
// 0, 512) so knn replicas stop monopolizing the top-5 rocprof slots.
// ---------------------------------------------------------------------------
__global__ __launch_bounds__(256) void knn6_kernel(const float* __restrict__ pos,
                                                   int* __restrict__ idx, int ofs)
{
    __shared__ float4 pts[NP];
    __shared__ float  sd[256 * 4];
    __shared__ float  thr[64];
    __shared__ int    ci[256 * 8];
    __shared__ int    cn[256];

    const int blk = blockIdx.x + ofs;
    const int b = blk >> 4;
    const int chunk = blk & 15;
    const int t = threadIdx.x;
    const float* gp = pos + (size_t)b * NP * 3;
    for (int q = t; q < NP; q += 256) {
        float x = gp[q * 3 + 0], y = gp[q * 3 + 1], z = gp[q * 3 + 2];
        pts[q] = make_float4(x, y, z, x * x + y * y + z * z);
    }
    __syncthreads();

    const int p = t >> 2;
    const int sub = t & 3;
    const int il = chunk * 64 + p;
    const float4 pi = pts[il];
    const float sqi = pi.w;

    float d0 = 1e30f, d1 = 1e30f, d2v = 1e30f, d3 = 1e30f;
#pragma unroll 4
    for (int it = 0; it < 256; ++it) {
        const int q = (it << 2) | sub;
        const float dq = dist2(pi, sqi, pts[q]);
        d3  = __builtin_amdgcn_fmed3f(dq, d2v, d3);
        d2v = __builtin_amdgcn_fmed3f(dq, d1, d2v);
        d1  = __builtin_amdgcn_fmed3f(dq, d0, d1);
        d0  = fminf(dq, d0);
    }
    {
        float* sp = &sd[t * 4];
        sp[0] = d0; sp[1] = d1; sp[2] = d2v; sp[3] = d3;
    }
    __syncthreads();

    if (t < 64) {
        float e0 = 1e30f, e1 = 1e30f, e2 = 1e30f, e3 = 1e30f, e4 = 1e30f, e5 = 1e30f;
#pragma unroll
        for (int s = 0; s < 4; ++s) {
            const float* q4 = &sd[(t * 4 + s) * 4];
#pragma unroll
            for (int k = 0; k < 4; ++k) {
                const float d = q4[k];
                e5 = __builtin_amdgcn_fmed3f(d, e4, e5);
                e4 = __builtin_amdgcn_fmed3f(d, e3, e4);
                e3 = __builtin_amdgcn_fmed3f(d, e2, e3);
                e2 = __builtin_amdgcn_fmed3f(d, e1, e2);
                e1 = __builtin_amdgcn_fmed3f(d, e0, e1);
                e0 = fminf(d, e0);
            }
        }
        thr[t] = e5;
    }
    __syncthreads();

    const float th = thr[p];
    int cnt = 0;
#pragma unroll 4
    for (int it = 0; it < 256; ++it) {
        const int q = (it << 2) | sub;
        const float dq = dist2(pi, sqi, pts[q]);
        if (dq <= th) {
            ci[t * 8 + (cnt & 7)] = q;
            ++cnt;
        }
    }
    cn[t] = (cnt > 8) ? 8 : cnt;
    __syncthreads();

    if (t < 64) {
        const float4 pit = pts[chunk * 64 + t];
        const float sqit = pit.w;
        float e0 = 1e30f, e1 = 1e30f, e2 = 1e30f, e3 = 1e30f, e4 = 1e30f, e5 = 1e30f;
        int j0 = 0x7fffffff, j1 = 0x7fffffff, j2 = 0x7fffffff,
            j3 = 0x7fffffff, j4 = 0x7fffffff, j5 = 0x7fffffff;
#pragma unroll
        for (int s = 0; s < 4; ++s) {
            const int tid = t * 4 + s;
            const int n = cn[tid];
            for (int e = 0; e < n; ++e) {
                const int q = ci[tid * 8 + e];
                const float d = dist2(pit, sqit, pts[q]);
                if (d < e5 || (d == e5 && q < j5)) {
                    if (d < e4 || (d == e4 && q < j4)) {
                        e5 = e4; j5 = j4;
                        if (d < e3 || (d == e3 && q < j3)) {
                            e4 = e3; j4 = j3;
                            if (d < e2 || (d == e2 && q < j2)) {
                                e3 = e2; j3 = j2;
                                if (d < e1 || (d == e1 && q < j1)) {
                                    e2 = e1; j2 = j1;
                                    if (d < e0 || (d == e0 && q < j0)) {
                                        e1 = e0; j1 = j0; e0 = d; j0 = q;
                                    } else { e1 = d; j1 = q; }
                                } else { e2 = d; j2 = q; }
                            } else { e3 = d; j3 = q; }
                        } else { e4 = d; j4 = q; }
                    } else { e5 = d; j5 = q; }
                }
            }
        }
        const int gb = b * NP;
        int* op = idx + (size_t)(gb + chunk * 64 + t) * 6;
        op[0] = gb + j0; op[1] = gb + j1; op[2] = gb + j2;
        op[3] = gb + j3; op[4] = gb + j4; op[5] = gb + j5;
    }
}

// ---------------------------------------------------------------------------
// Kernel 2: layer-1 prep (standalone again): U1 = b1 + pos@(W1a-W1c);
// Vpos = pos@(W1b+W1c).
// ---------------------------------------------------------------------------
__global__ __launch_bounds__(256) void prep1_kernel(
    const float* __restrict__ pos, const float* __restrict__ W1,
    const float* __restrict__ b1, float* __restrict__ Uout,
    float* __restrict__ Vout)
{
    const int gid = blockIdx.x * 256 + threadIdx.x;
    const int i = gid >> 6;
    const int c = gid & 63;
    const float px = pos[i * 3 + 0], py = pos[i * 3 + 1], pz = pos[i * 3 + 2];
    float u = b1[c];
    u = fmaf(px, W1[0 * 64 + c] - W1[6 * 64 + c], u);
    u = fmaf(py, W1[1 * 64 + c] - W1[7 * 64 + c], u);
    u = fmaf(pz, W1[2 * 64 + c] - W1[8 * 64 + c], u);
    Uout[(size_t)i * 64 + c] = u;
    float v =      px * (W1[3 * 64 + c] + W1[6 * 64 + c]);
    v = fmaf(py, W1[4 * 64 + c] + W1[7 * 64 + c], v);
    v = fmaf(pz, W1[5 * 64 + c] + W1[8 * 64 + c], v);
    Vout[(size_t)i * 64 + c] = v;
}

// ---------------------------------------------------------------------------
// Kernel 3: U/V precompute via MFMA (R13 form: A-frags hoisted, 1 tile/wave,
// grid 1024). Block 0 optionally zeroes the pooled accumulator.
// ---------------------------------------------------------------------------
__global__ __launch_bounds__(256) void uv_mfma_kernel(
    float* __restrict__ h, float* __restrict__ Vout,
    const float* __restrict__ pos,
    const float* __restrict__ W1, const float* __restrict__ b1,
    float* __restrict__ pooled_zero)
{
    const int t = threadIdx.x;
    const int lane = t & 63;
    const int wv = __builtin_amdgcn_readfirstlane(t >> 6);
    const int col = lane & 15;
    const int quad = lane >> 4;

    if (pooled_zero != nullptr && blockIdx.x == 0) {
#pragma unroll
        for (int i = 0; i < 16; ++i) pooled_zero[i * 256 + t] = 0.0f;
    }

    const int pb = (blockIdx.x * 4 + wv) * 16;

    v8s ah[2], al[2];
#pragma unroll
    for (int ks = 0; ks < 2; ++ks) {
        float w[8];
        const float4 f0 = *(const float4*)(h + (size_t)(pb + col) * 64 + ks * 32 + quad * 8);
        const float4 f1 = *(const float4*)(h + (size_t)(pb + col) * 64 + ks * 32 + quad * 8 + 4);
        w[0] = f0.x; w[1] = f0.y; w[2] = f0.z; w[3] = f0.w;
        w[4] = f1.x; w[5] = f1.y; w[6] = f1.z; w[7] = f1.w;
        pack8(w, ah[ks], al[ks]);
    }

    float prx[4], pry[4], prz[4];
#pragma unroll
    for (int r = 0; r < 4; ++r) {
        const int pt = pb + quad * 4 + r;
        prx[r] = pos[pt * 3 + 0];
        pry[r] = pos[pt * 3 + 1];
        prz[r] = pos[pt * 3 + 2];
    }
    float wcx[4], wcy[4], wcz[4], b1v[4];
#pragma unroll
    for (int nt = 0; nt < 4; ++nt) {
        wcx[nt] = W1[128 * 64 + nt * 16 + col];
        wcy[nt] = W1[129 * 64 + nt * 16 + col];
        wcz[nt] = W1[130 * 64 + nt * 16 + col];
        b1v[nt] = b1[nt * 16 + col];
    }

    for (int half = 1; half >= 0; --half) {
        v8s bh[4][2], bl[4][2];
#pragma unroll
        for (int nt = 0; nt < 4; ++nt) {
#pragma unroll
            for (int ks = 0; ks < 2; ++ks) {
                float w[8];
#pragma unroll
                for (int j = 0; j < 8; ++j)
                    w[j] = W1[(size_t)(half * 64 + ks * 32 + quad * 8 + j) * 64 + nt * 16 + col];
                pack8(w, bh[nt][ks], bl[nt][ks]);
            }
        }

        f32x4 acc[4];
#pragma unroll
        for (int nt = 0; nt < 4; ++nt) acc[nt] = (f32x4){0.f, 0.f, 0.f, 0.f};
#pragma unroll
        for (int nt = 0; nt < 4; ++nt) {
#pragma unroll
            for (int ks = 0; ks < 2; ++ks) {
                acc[nt] = __builtin_amdgcn_mfma_f32_16x16x32_bf16(ah[ks], bh[nt][ks], acc[nt], 0, 0, 0);
                acc[nt] = __builtin_amdgcn_mfma_f32_16x16x32_bf16(ah[ks], bl[nt][ks], acc[nt], 0, 0, 0);
                acc[nt] = __builtin_amdgcn_mfma_f32_16x16x32_bf16(al[ks], bh[nt][ks], acc[nt], 0, 0, 0);
            }
        }

        float* outp = half ? Vout : h;
#pragma unroll
        for (int nt = 0; nt < 4; ++nt) {
            const float* a = (const float*)&acc[nt];
#pragma unroll
            for (int r = 0; r < 4; ++r) {
                float dotp = fmaf(prz[r], wcz[nt], fmaf(pry[r], wcy[nt], prx[r] * wcx[nt]));
                float val = half ? (a[r] + dotp) : (a[r] + b1v[nt] - dotp);
                outp[(size_t)(pb + quad * 4 + r) * 64 + nt * 16 + col] = val;
            }
        }
    }
}

// ---------------------------------------------------------------------------
// Kernel 4: unified MFMA edge kernel (R10 form; R13 grids).
// ---------------------------------------------------------------------------
template <int PT, int KP, int KREAL, bool ATOMIC>
__global__ __launch_bounds__(256) void edge_mfma_kernel(
    const float* __restrict__ U, const float* __restrict__ V,
    const int* __restrict__ idx,
    const float* __restrict__ W2, const float* __restrict__ b2,
    float* __restrict__ outp, int TPW)
{
    __shared__ char ldsbuf[4 * 16 * 272];
    const int t = threadIdx.x;
    const int lane = t & 63;
    const int wv = __builtin_amdgcn_readfirstlane(t >> 6);
    char* base = &ldsbuf[wv * 16 * 272];
    const int col = lane & 15;
    const int quad = lane >> 4;
    constexpr int KSH = (KP == 8) ? 3 : 2;

    v8s bh[4][2], bl[4][2];
#pragma unroll
    for (int nt = 0; nt < 4; ++nt) {
#pragma unroll
        for (int ks = 0; ks < 2; ++ks) {
            float w[8];
#pragma unroll
            for (int j = 0; j < 8; ++j)
                w[j] = W2[(size_t)(ks * 32 + quad * 8 + j) * 64 + nt * 16 + col];
            pack8(w, bh[nt][ks], bl[nt][ks]);
        }
    }
    float b2v[4];
#pragma unroll
    for (int nt = 0; nt < 4; ++nt) b2v[nt] = b2[nt * 16 + col];

    for (int tt = 0; tt < TPW; ++tt) {
        const int tile = (blockIdx.x * 4 + wv) * TPW + tt;
        const int pb = tile * PT;

        float u[PT];
#pragma unroll
        for (int p = 0; p < PT; ++p) u[p] = U[(size_t)(pb + p) * 64 + lane];

#pragma unroll
        for (int e = 0; e < 16; ++e) {
            const int p = e >> KSH;
            int k = e & (KP - 1);
            if (k >= KREAL) k = 0;
            const int j = __builtin_amdgcn_readfirstlane(idx[(size_t)(pb + p) * 6 + k]);
            float tv = u[p] + V[(size_t)j * 64 + lane];
            tv = fmaxf(tv, 0.0f);
            const unsigned int tu = __float_as_uint(tv);
            const unsigned int hi = tu & 0xffff0000u;
            const float lo = tv - __uint_as_float(hi);
            *((short*)(base + e * 272) + lane)       = (short)(hi >> 16);
            *((short*)(base + e * 272 + 128) + lane) = (short)(__float_as_uint(lo) >> 16);
        }
        __builtin_amdgcn_wave_barrier();
        __builtin_amdgcn_s_waitcnt(0xc07f);

        v8s ah[2], al[2];
#pragma unroll
        for (int ks = 0; ks < 2; ++ks) {
            ah[ks] = *(const v8s*)(base + (lane & 15) * 272 + ks * 64 + quad * 16);
            al[ks] = *(const v8s*)(base + (lane & 15) * 272 + 128 + ks * 64 + quad * 16);
        }

        f32x4 acc[4];
#pragma unroll
        for (int nt = 0; nt < 4; ++nt) acc[nt] = (f32x4){0.f, 0.f, 0.f, 0.f};
#pragma unroll
        for (int nt = 0; nt < 4; ++nt) {
#pragma unroll
            for (int ks = 0; ks < 2; ++ks) {
                acc[nt] = __builtin_amdgcn_mfma_f32_16x16x32_bf16(ah[ks], bh[nt][ks], acc[nt], 0, 0, 0);
                acc[nt] = __builtin_amdgcn_mfma_f32_16x16x32_bf16(ah[ks], bl[nt][ks], acc[nt], 0, 0, 0);
                acc[nt] = __builtin_amdgcn_mfma_f32_16x16x32_bf16(al[ks], bh[nt][ks], acc[nt], 0, 0, 0);
            }
        }

#pragma unroll
        for (int nt = 0; nt < 4; ++nt) {
            float m = fmaxf(fmaxf(acc[nt].x, acc[nt].y), fmaxf(acc[nt].z, acc[nt].w));
            if (ATOMIC) {
                const float z0 = fmaxf(m + b2v[nt], 0.0f);
                float zm = fmaxf(z0, __shfl_xor(z0, 16));
                zm = fmaxf(zm, __shfl_xor(zm, 32));
                if (quad == 0) {
                    const int g = pb >> 10;
                    atomicMax((unsigned int*)(outp + (size_t)g * 64 + nt * 16 + col),
                              __float_as_uint(zm));
                }
            } else if (KP == 4) {
                const float z = fmaxf(m + b2v[nt], 0.0f);
                outp[(size_t)(pb + quad) * 64 + nt * 16 + col] = z;
            } else {
                m = fmaxf(m, __shfl_xor(m, 16));
                const float z = fmaxf(m + b2v[nt], 0.0f);
                if ((lane & 16) == 0)
                    outp[(size_t)(pb + (lane >> 5)) * 64 + nt * 16 + col] = z;
            }
        }
    }
}

// ---------------------------------------------------------------------------
// Kernel 5: final 64->6 regression from pooled. 6 blocks x 64 threads.
// ---------------------------------------------------------------------------
__global__ __launch_bounds__(64) void reg_kernel(
    const float* __restrict__ pooled, const float* __restrict__ regW,
    const float* __restrict__ regb, float* __restrict__ out)
{
    const int t = blockIdx.x * 64 + threadIdx.x;
    const int b = t / 6;
    const int o = t - b * 6;
    if (t < NB * 6) {
        float z = regb[o];
        const float* pb = pooled + (size_t)b * 64;
        for (int c = 0; c < 64; ++c) z = fmaf(pb[c], regW[c * 6 + o], z);
        out[b * 6 + o] = z;
    }
}

// ---------------------------------------------------------------------------
extern "C" void kernel_launch(void* const* d_in, const int* in_sizes, int n_in,
                              void* d_out, int out_size, void* d_ws, size_t ws_size,
                              hipStream_t stream)
{
    (void)in_sizes; (void)n_in; (void)out_size; (void)ws_size;
    const float* pos   = (const float*)d_in[1];
    const float* c1W1  = (const float*)d_in[3];
    const float* c1b1  = (const float*)d_in[4];
    const float* c1W2  = (const float*)d_in[5];
    const float* c1b2  = (const float*)d_in[6];
    const float* c2W1  = (const float*)d_in[7];
    const float* c2b1  = (const float*)d_in[8];
    const float* c2W2  = (const float*)d_in[9];
    const float* c2b2  = (const float*)d_in[10];
    const float* c3W1  = (const float*)d_in[11];
    const float* c3b1  = (const float*)d_in[12];
    const float* c3W2  = (const float*)d_in[13];
    const float* c3b2  = (const float*)d_in[14];
    const float* regW  = (const float*)d_in[15];
    const float* regb  = (const float*)d_in[16];
    float* out = (float*)d_out;

    // workspace: idx | A | C | D   (A,C,D are 65536x64 fp32)
    // pooled (16 KB) reuses the head of A; zeroed by uv3's block 0.
    char* ws = (char*)d_ws;
    int*   idx = (int*)ws;
    float* A = (float*)(ws + 1572864);
    float* C = (float*)(ws + 1572864 + 16777216);
    float* D = (float*)(ws + 1572864 + 2 * 16777216);
    float* pooled = A;

    // prep: U1 -> D, Vpos -> C ; kNN split into two half-grids
    prep1_kernel<<<NPTS * 64 / 256, 256, 0, stream>>>(pos, c1W1, c1b1, D, C);
    knn6_kernel<<<512, 256, 0, stream>>>(pos, idx, 0);
    knn6_kernel<<<512, 256, 0, stream>>>(pos, idx, 512);

    // layer 1: edges (PT=2, KP=8, K=6) -> A (h1)
    edge_mfma_kernel<2, 8, 6, false><<<2048, 256, 0, stream>>>(
        D, C, idx, c1W2, c1b2, A, 4);

    // layer 2: U2 in-place over A, V2 -> C; edges -> D (h2)
    uv_mfma_kernel<<<1024, 256, 0, stream>>>(A, C, pos, c2W1, c2b1, nullptr);
    edge_mfma_kernel<4, 4, 4, false><<<2048, 256, 0, stream>>>(
        A, C, idx, c2W2, c2b2, D, 2);

    // layer 3: U3 in-place over D, V3 -> C (block 0 zeroes pooled);
    // edges -> atomic max into pooled
    uv_mfma_kernel<<<1024, 256, 0, stream>>>(D, C, pos, c3W1, c3b1, pooled);
    edge_mfma_kernel<4, 4, 3, true><<<2048, 256, 0, stream>>>(
        D, C, idx, c3W2, c3b2, pooled, 2);

    // final regression
    reg_kernel<<<6, 64, 0, stream>>>(pooled, regW, regb, out);
}

// Round 15
// 225.630 us; speedup vs baseline: 1.1789x; 1.1789x over previous
//
#include <hip/hip_runtime.h>
#include <cstddef>

#define NB 64
#define NP 1024
#define NPTS (NB * NP)

typedef __attribute__((ext_vector_type(8))) short v8s;
typedef __attribute__((ext_vector_type(4))) float f32x4;

__device__ __forceinline__ float dist2(const float4 pi, const float sqi, const float4 pq) {
    const float dot = fmaf(pi.z, pq.z, fmaf(pi.y, pq.y, pi.x * pq.x));
    return fmaf(-2.0f, dot, sqi + pq.w);
}

__device__ __forceinline__ void pack8(const float* w, v8s& hv, v8s& lv) {
    union { v8s v; unsigned int u[4]; } H, L;
#pragma unroll
    for (int p = 0; p < 4; ++p) {
        unsigned int a = __float_as_uint(w[2 * p]);
        unsigned int b = __float_as_uint(w[2 * p + 1]);
        unsigned int ha = a & 0xffff0000u, hb = b & 0xffff0000u;
        H.u[p] = (ha >> 16) | hb;
        float la = w[2 * p] - __uint_as_float(ha);
        float lb = w[2 * p + 1] - __uint_as_float(hb);
        L.u[p] = (__float_as_uint(la) >> 16) | (__float_as_uint(lb) & 0xffff0000u);
    }
    hv = H.v; lv = L.v;
}

// ---------------------------------------------------------------------------
// Kernel 1: top-6 kNN, two-pass, single 1024-block launch (R12 proven, 48us).
// ---------------------------------------------------------------------------
__global__ __launch_bounds__(256) void knn6_kernel(const float* __restrict__ pos,
                                                   int* __restrict__ idx)
{
    __shared__ float4 pts[NP];
    __shared__ float  sd[256 * 4];
    __shared__ float  thr[64];
    __shared__ int    ci[256 * 8];
    __shared__ int    cn[256];

    const int blk = blockIdx.x;
    const int b = blk >> 4;
    const int chunk = blk & 15;
    const int t = threadIdx.x;
    const float* gp = pos + (size_t)b * NP * 3;
    for (int q = t; q < NP; q += 256) {
        float x = gp[q * 3 + 0], y = gp[q * 3 + 1], z = gp[q * 3 + 2];
        pts[q] = make_float4(x, y, z, x * x + y * y + z * z);
    }
    __syncthreads();

    const int p = t >> 2;
    const int sub = t & 3;
    const int il = chunk * 64 + p;
    const float4 pi = pts[il];
    const float sqi = pi.w;

    float d0 = 1e30f, d1 = 1e30f, d2v = 1e30f, d3 = 1e30f;
#pragma unroll 4
    for (int it = 0; it < 256; ++it) {
        const int q = (it << 2) | sub;
        const float dq = dist2(pi, sqi, pts[q]);
        d3  = __builtin_amdgcn_fmed3f(dq, d2v, d3);
        d2v = __builtin_amdgcn_fmed3f(dq, d1, d2v);
        d1  = __builtin_amdgcn_fmed3f(dq, d0, d1);
        d0  = fminf(dq, d0);
    }
    {
        float* sp = &sd[t * 4];
        sp[0] = d0; sp[1] = d1; sp[2] = d2v; sp[3] = d3;
    }
    __syncthreads();

    if (t < 64) {
        float e0 = 1e30f, e1 = 1e30f, e2 = 1e30f, e3 = 1e30f, e4 = 1e30f, e5 = 1e30f;
#pragma unroll
        for (int s = 0; s < 4; ++s) {
            const float* q4 = &sd[(t * 4 + s) * 4];
#pragma unroll
            for (int k = 0; k < 4; ++k) {
                const float d = q4[k];
                e5 = __builtin_amdgcn_fmed3f(d, e4, e5);
                e4 = __builtin_amdgcn_fmed3f(d, e3, e4);
                e3 = __builtin_amdgcn_fmed3f(d, e2, e3);
                e2 = __builtin_amdgcn_fmed3f(d, e1, e2);
                e1 = __builtin_amdgcn_fmed3f(d, e0, e1);
                e0 = fminf(d, e0);
            }
        }
        thr[t] = e5;
    }
    __syncthreads();

    const float th = thr[p];
    int cnt = 0;
#pragma unroll 4
    for (int it = 0; it < 256; ++it) {
        const int q = (it << 2) | sub;
        const float dq = dist2(pi, sqi, pts[q]);
        if (dq <= th) {
            ci[t * 8 + (cnt & 7)] = q;
            ++cnt;
        }
    }
    cn[t] = (cnt > 8) ? 8 : cnt;
    __syncthreads();

    if (t < 64) {
        const float4 pit = pts[chunk * 64 + t];
        const float sqit = pit.w;
        float e0 = 1e30f, e1 = 1e30f, e2 = 1e30f, e3 = 1e30f, e4 = 1e30f, e5 = 1e30f;
        int j0 = 0x7fffffff, j1 = 0x7fffffff, j2 = 0x7fffffff,
            j3 = 0x7fffffff, j4 = 0x7fffffff, j5 = 0x7fffffff;
#pragma unroll
        for (int s = 0; s < 4; ++s) {
            const int tid = t * 4 + s;
            const int n = cn[tid];
            for (int e = 0; e < n; ++e) {
                const int q = ci[tid * 8 + e];
                const float d = dist2(pit, sqit, pts[q]);
                if (d < e5 || (d == e5 && q < j5)) {
                    if (d < e4 || (d == e4 && q < j4)) {
                        e5 = e4; j5 = j4;
                        if (d < e3 || (d == e3 && q < j3)) {
                            e4 = e3; j4 = j3;
                            if (d < e2 || (d == e2 && q < j2)) {
                                e3 = e2; j3 = j2;
                                if (d < e1 || (d == e1 && q < j1)) {
                                    e2 = e1; j2 = j1;
                                    if (d < e0 || (d == e0 && q < j0)) {
                                        e1 = e0; j1 = j0; e0 = d; j0 = q;
                                    } else { e1 = d; j1 = q; }
                                } else { e2 = d; j2 = q; }
                            } else { e3 = d; j3 = q; }
                        } else { e4 = d; j4 = q; }
                    } else { e5 = d; j5 = q; }
                }
            }
        }
        const int gb = b * NP;
        int* op = idx + (size_t)(gb + chunk * 64 + t) * 6;
        op[0] = gb + j0; op[1] = gb + j1; op[2] = gb + j2;
        op[3] = gb + j3; op[4] = gb + j4; op[5] = gb + j5;
    }
}

// ---------------------------------------------------------------------------
// Kernel 2: layer-1 prep: U1 = b1 + pos@(W1a-W1c); Vpos = pos@(W1b+W1c).
// ---------------------------------------------------------------------------
__global__ __launch_bounds__(256) void prep1_kernel(
    const float* __restrict__ pos, const float* __restrict__ W1,
    const float* __restrict__ b1, float* __restrict__ Uout,
    float* __restrict__ Vout)
{
    const int gid = blockIdx.x * 256 + threadIdx.x;
    const int i = gid >> 6;
    const int c = gid & 63;
    const float px = pos[i * 3 + 0], py = pos[i * 3 + 1], pz = pos[i * 3 + 2];
    float u = b1[c];
    u = fmaf(px, W1[0 * 64 + c] - W1[6 * 64 + c], u);
    u = fmaf(py, W1[1 * 64 + c] - W1[7 * 64 + c], u);
    u = fmaf(pz, W1[2 * 64 + c] - W1[8 * 64 + c], u);
    Uout[(size_t)i * 64 + c] = u;
    float v =      px * (W1[3 * 64 + c] + W1[6 * 64 + c]);
    v = fmaf(py, W1[4 * 64 + c] + W1[7 * 64 + c], v);
    v = fmaf(pz, W1[5 * 64 + c] + W1[8 * 64 + c], v);
    Vout[(size_t)i * 64 + c] = v;
}

// ---------------------------------------------------------------------------
// Kernel 3: U/V precompute via MFMA. XCD-SWIZZLED: blockIdx%8 (the XCD slot)
// selects a fixed set of 8 graphs, so each XCD's 4MB L2 only sees 8 graphs'
// rows (2MB working set). Pure index permutation — math unchanged.
// Grid 1024 = 8 xcd-slots x 8 graphs x 16 sub-blocks.
// ---------------------------------------------------------------------------
__global__ __launch_bounds__(256) void uv_mfma_kernel(
    float* __restrict__ h, float* __restrict__ Vout,
    const float* __restrict__ pos,
    const float* __restrict__ W1, const float* __restrict__ b1,
    float* __restrict__ pooled_zero)
{
    const int t = threadIdx.x;
    const int lane = t & 63;
    const int wv = __builtin_amdgcn_readfirstlane(t >> 6);
    const int col = lane & 15;
    const int quad = lane >> 4;

    if (pooled_zero != nullptr && blockIdx.x == 0) {
#pragma unroll
        for (int i = 0; i < 16; ++i) pooled_zero[i * 256 + t] = 0.0f;
    }

    const int x = blockIdx.x & 7;        // XCD slot
    const int r = blockIdx.x >> 3;       // 0..127
    const int g = x * 8 + (r & 7);       // graph
    const int sb = r >> 3;               // 0..15 sub-block
    const int pb = g * NP + (sb * 4 + wv) * 16;

    v8s ah[2], al[2];
#pragma unroll
    for (int ks = 0; ks < 2; ++ks) {
        float w[8];
        const float4 f0 = *(const float4*)(h + (size_t)(pb + col) * 64 + ks * 32 + quad * 8);
        const float4 f1 = *(const float4*)(h + (size_t)(pb + col) * 64 + ks * 32 + quad * 8 + 4);
        w[0] = f0.x; w[1] = f0.y; w[2] = f0.z; w[3] = f0.w;
        w[4] = f1.x; w[5] = f1.y; w[6] = f1.z; w[7] = f1.w;
        pack8(w, ah[ks], al[ks]);
    }

    float prx[4], pry[4], prz[4];
#pragma unroll
    for (int r2 = 0; r2 < 4; ++r2) {
        const int pt = pb + quad * 4 + r2;
        prx[r2] = pos[pt * 3 + 0];
        pry[r2] = pos[pt * 3 + 1];
        prz[r2] = pos[pt * 3 + 2];
    }
    float wcx[4], wcy[4], wcz[4], b1v[4];
#pragma unroll
    for (int nt = 0; nt < 4; ++nt) {
        wcx[nt] = W1[128 * 64 + nt * 16 + col];
        wcy[nt] = W1[129 * 64 + nt * 16 + col];
        wcz[nt] = W1[130 * 64 + nt * 16 + col];
        b1v[nt] = b1[nt * 16 + col];
    }

    for (int half = 1; half >= 0; --half) {
        v8s bh[4][2], bl[4][2];
#pragma unroll
        for (int nt = 0; nt < 4; ++nt) {
#pragma unroll
            for (int ks = 0; ks < 2; ++ks) {
                float w[8];
#pragma unroll
                for (int j = 0; j < 8; ++j)
                    w[j] = W1[(size_t)(half * 64 + ks * 32 + quad * 8 + j) * 64 + nt * 16 + col];
                pack8(w, bh[nt][ks], bl[nt][ks]);
            }
        }

        f32x4 acc[4];
#pragma unroll
        for (int nt = 0; nt < 4; ++nt) acc[nt] = (f32x4){0.f, 0.f, 0.f, 0.f};
#pragma unroll
        for (int nt = 0; nt < 4; ++nt) {
#pragma unroll
            for (int ks = 0; ks < 2; ++ks) {
                acc[nt] = __builtin_amdgcn_mfma_f32_16x16x32_bf16(ah[ks], bh[nt][ks], acc[nt], 0, 0, 0);
                acc[nt] = __builtin_amdgcn_mfma_f32_16x16x32_bf16(ah[ks], bl[nt][ks], acc[nt], 0, 0, 0);
                acc[nt] = __builtin_amdgcn_mfma_f32_16x16x32_bf16(al[ks], bh[nt][ks], acc[nt], 0, 0, 0);
            }
        }

        float* outp = half ? Vout : h;
#pragma unroll
        for (int nt = 0; nt < 4; ++nt) {
            const float* a = (const float*)&acc[nt];
#pragma unroll
            for (int r2 = 0; r2 < 4; ++r2) {
                float dotp = fmaf(prz[r2], wcz[nt], fmaf(pry[r2], wcy[nt], prx[r2] * wcx[nt]));
                float val = half ? (a[r2] + dotp) : (a[r2] + b1v[nt] - dotp);
                outp[(size_t)(pb + quad * 4 + r2) * 64 + nt * 16 + col] = val;
            }
        }
    }
}

// ---------------------------------------------------------------------------
// Kernel 4: unified MFMA edge kernel, XCD-SWIZZLED (blockIdx%8 -> 8 graphs):
// the random V[j] gathers of a graph stay within one XCD's L2.
// Grid 2048 = 8 xcd-slots x 8 graphs x 32 sub-blocks.
// ---------------------------------------------------------------------------
template <int PT, int KP, int KREAL, int TPW, bool ATOMIC>
__global__ __launch_bounds__(256) void edge_mfma_kernel(
    const float* __restrict__ U, const float* __restrict__ V,
    const int* __restrict__ idx,
    const float* __restrict__ W2, const float* __restrict__ b2,
    float* __restrict__ outp)
{
    __shared__ char ldsbuf[4 * 16 * 272];
    const int t = threadIdx.x;
    const int lane = t & 63;
    const int wv = __builtin_amdgcn_readfirstlane(t >> 6);
    char* base = &ldsbuf[wv * 16 * 272];
    const int col = lane & 15;
    const int quad = lane >> 4;
    constexpr int KSH = (KP == 8) ? 3 : 2;

    v8s bh[4][2], bl[4][2];
#pragma unroll
    for (int nt = 0; nt < 4; ++nt) {
#pragma unroll
        for (int ks = 0; ks < 2; ++ks) {
            float w[8];
#pragma unroll
            for (int j = 0; j < 8; ++j)
                w[j] = W2[(size_t)(ks * 32 + quad * 8 + j) * 64 + nt * 16 + col];
            pack8(w, bh[nt][ks], bl[nt][ks]);
        }
    }
    float b2v[4];
#pragma unroll
    for (int nt = 0; nt < 4; ++nt) b2v[nt] = b2[nt * 16 + col];

    const int x = blockIdx.x & 7;        // XCD slot
    const int r = blockIdx.x >> 3;       // 0..255
    const int g = x * 8 + (r & 7);       // graph
    const int sb = r >> 3;               // 0..31 sub-block

    for (int tt = 0; tt < TPW; ++tt) {
        const int tig = (sb * 4 + wv) * TPW + tt;   // tile in graph
        const int pb = g * NP + tig * PT;

        float u[PT];
#pragma unroll
        for (int p = 0; p < PT; ++p) u[p] = U[(size_t)(pb + p) * 64 + lane];

#pragma unroll
        for (int e = 0; e < 16; ++e) {
            const int p = e >> KSH;
            int k = e & (KP - 1);
            if (k >= KREAL) k = 0;
            const int j = __builtin_amdgcn_readfirstlane(idx[(size_t)(pb + p) * 6 + k]);
            float tv = u[p] + V[(size_t)j * 64 + lane];
            tv = fmaxf(tv, 0.0f);
            const unsigned int tu = __float_as_uint(tv);
            const unsigned int hi = tu & 0xffff0000u;
            const float lo = tv - __uint_as_float(hi);
            *((short*)(base + e * 272) + lane)       = (short)(hi >> 16);
            *((short*)(base + e * 272 + 128) + lane) = (short)(__float_as_uint(lo) >> 16);
        }
        __builtin_amdgcn_wave_barrier();
        __builtin_amdgcn_s_waitcnt(0xc07f);

        v8s ah[2], al[2];
#pragma unroll
        for (int ks = 0; ks < 2; ++ks) {
            ah[ks] = *(const v8s*)(base + (lane & 15) * 272 + ks * 64 + quad * 16);
            al[ks] = *(const v8s*)(base + (lane & 15) * 272 + 128 + ks * 64 + quad * 16);
        }

        f32x4 acc[4];
#pragma unroll
        for (int nt = 0; nt < 4; ++nt) acc[nt] = (f32x4){0.f, 0.f, 0.f, 0.f};
#pragma unroll
        for (int nt = 0; nt < 4; ++nt) {
#pragma unroll
            for (int ks = 0; ks < 2; ++ks) {
                acc[nt] = __builtin_amdgcn_mfma_f32_16x16x32_bf16(ah[ks], bh[nt][ks], acc[nt], 0, 0, 0);
                acc[nt] = __builtin_amdgcn_mfma_f32_16x16x32_bf16(ah[ks], bl[nt][ks], acc[nt], 0, 0, 0);
                acc[nt] = __builtin_amdgcn_mfma_f32_16x16x32_bf16(al[ks], bh[nt][ks], acc[nt], 0, 0, 0);
            }
        }

#pragma unroll
        for (int nt = 0; nt < 4; ++nt) {
            float m = fmaxf(fmaxf(acc[nt].x, acc[nt].y), fmaxf(acc[nt].z, acc[nt].w));
            if (ATOMIC) {
                const float z0 = fmaxf(m + b2v[nt], 0.0f);
                float zm = fmaxf(z0, __shfl_xor(z0, 16));
                zm = fmaxf(zm, __shfl_xor(zm, 32));
                if (quad == 0) {
                    atomicMax((unsigned int*)(outp + (size_t)g * 64 + nt * 16 + col),
                              __float_as_uint(zm));
                }
            } else if (KP == 4) {
                const float z = fmaxf(m + b2v[nt], 0.0f);
                outp[(size_t)(pb + quad) * 64 + nt * 16 + col] = z;
            } else {
                m = fmaxf(m, __shfl_xor(m, 16));
                const float z = fmaxf(m + b2v[nt], 0.0f);
                if ((lane & 16) == 0)
                    outp[(size_t)(pb + (lane >> 5)) * 64 + nt * 16 + col] = z;
            }
        }
    }
}

// ---------------------------------------------------------------------------
// Kernel 5: final 64->6 regression from pooled. 6 blocks x 64 threads.
// ---------------------------------------------------------------------------
__global__ __launch_bounds__(64) void reg_kernel(
    const float* __restrict__ pooled, const float* __restrict__ regW,
    const float* __restrict__ regb, float* __restrict__ out)
{
    const int t = blockIdx.x * 64 + threadIdx.x;
    const int b = t / 6;
    const int o = t - b * 6;
    if (t < NB * 6) {
        float z = regb[o];
        const float* pb = pooled + (size_t)b * 64;
        for (int c = 0; c < 64; ++c) z = fmaf(pb[c], regW[c * 6 + o], z);
        out[b * 6 + o] = z;
    }
}

// ---------------------------------------------------------------------------
extern "C" void kernel_launch(void* const* d_in, const int* in_sizes, int n_in,
                              void* d_out, int out_size, void* d_ws, size_t ws_size,
                              hipStream_t stream)
{
    (void)in_sizes; (void)n_in; (void)out_size; (void)ws_size;
    const float* pos   = (const float*)d_in[1];
    const float* c1W1  = (const float*)d_in[3];
    const float* c1b1  = (const float*)d_in[4];
    const float* c1W2  = (const float*)d_in[5];
    const float* c1b2  = (const float*)d_in[6];
    const float* c2W1  = (const float*)d_in[7];
    const float* c2b1  = (const float*)d_in[8];
    const float* c2W2  = (const float*)d_in[9];
    const float* c2b2  = (const float*)d_in[10];
    const float* c3W1  = (const float*)d_in[11];
    const float* c3b1  = (const float*)d_in[12];
    const float* c3W2  = (const float*)d_in[13];
    const float* c3b2  = (const float*)d_in[14];
    const float* regW  = (const float*)d_in[15];
    const float* regb  = (const float*)d_in[16];
    float* out = (float*)d_out;

    // workspace: idx | A | C | D   (A,C,D are 65536x64 fp32)
    // pooled (16 KB) reuses the head of A; zeroed by uv3's block 0.
    char* ws = (char*)d_ws;
    int*   idx = (int*)ws;
    float* A = (float*)(ws + 1572864);
    float* C = (float*)(ws + 1572864 + 16777216);
    float* D = (float*)(ws + 1572864 + 2 * 16777216);
    float* pooled = A;

    // prep: U1 -> D, Vpos -> C ; kNN single launch (proven 48us)
    prep1_kernel<<<NPTS * 64 / 256, 256, 0, stream>>>(pos, c1W1, c1b1, D, C);
    knn6_kernel<<<NB * 16, 256, 0, stream>>>(pos, idx);

    // layer 1: edges (PT=2, KP=8, K=6) -> A (h1)
    edge_mfma_kernel<2, 8, 6, 4, false><<<2048, 256, 0, stream>>>(
        D, C, idx, c1W2, c1b2, A);

    // layer 2: U2 in-place over A, V2 -> C; edges -> D (h2)
    uv_mfma_kernel<<<1024, 256, 0, stream>>>(A, C, pos, c2W1, c2b1, nullptr);
    edge_mfma_kernel<4, 4, 4, 2, false><<<2048, 256, 0, stream>>>(
        A, C, idx, c2W2, c2b2, D);

    // layer 3: U3 in-place over D, V3 -> C (block 0 zeroes pooled);
    // edges -> atomic max into pooled
    uv_mfma_kernel<<<1024, 256, 0, stream>>>(D, C, pos, c3W1, c3b1, pooled);
    edge_mfma_kernel<4, 4, 3, 2, true><<<2048, 256, 0, stream>>>(
        D, C, idx, c3W2, c3b2, pooled);

    // final regression
    reg_kernel<<<6, 64, 0, stream>>>(pooled, regW, regb, out);
}

// Round 16
// 223.792 us; speedup vs baseline: 1.1885x; 1.0082x over previous
//
#include <hip/hip_runtime.h>
#include <cstddef>

#define NB 64
#define NP 1024
#define NPTS (NB * NP)

typedef __attribute__((ext_vector_type(8))) short v8s;
typedef __attribute__((ext_vector_type(4))) float f32x4;

__device__ __forceinline__ float dist2(const float4 pi, const float sqi, const float4 pq) {
    const float dot = fmaf(pi.z, pq.z, fmaf(pi.y, pq.y, pi.x * pq.x));
    return fmaf(-2.0f, dot, sqi + pq.w);
}

__device__ __forceinline__ void pack8(const float* w, v8s& hv, v8s& lv) {
    union { v8s v; unsigned int u[4]; } H, L;
#pragma unroll
    for (int p = 0; p < 4; ++p) {
        unsigned int a = __float_as_uint(w[2 * p]);
        unsigned int b = __float_as_uint(w[2 * p + 1]);
        unsigned int ha = a & 0xffff0000u, hb = b & 0xffff0000u;
        H.u[p] = (ha >> 16) | hb;
        float la = w[2 * p] - __uint_as_float(ha);
        float lb = w[2 * p + 1] - __uint_as_float(hb);
        L.u[p] = (__float_as_uint(la) >> 16) | (__float_as_uint(lb) & 0xffff0000u);
    }
    hv = H.v; lv = L.v;
}

// ---------------------------------------------------------------------------
// Kernel 1: top-6 kNN, two-pass, single 1024-block launch (proven 48us).
// ---------------------------------------------------------------------------
__global__ __launch_bounds__(256) void knn6_kernel(const float* __restrict__ pos,
                                                   int* __restrict__ idx)
{
    __shared__ float4 pts[NP];
    __shared__ float  sd[256 * 4];
    __shared__ float  thr[64];
    __shared__ int    ci[256 * 8];
    __shared__ int    cn[256];

    const int blk = blockIdx.x;
    const int b = blk >> 4;
    const int chunk = blk & 15;
    const int t = threadIdx.x;
    const float* gp = pos + (size_t)b * NP * 3;
    for (int q = t; q < NP; q += 256) {
        float x = gp[q * 3 + 0], y = gp[q * 3 + 1], z = gp[q * 3 + 2];
        pts[q] = make_float4(x, y, z, x * x + y * y + z * z);
    }
    __syncthreads();

    const int p = t >> 2;
    const int sub = t & 3;
    const int il = chunk * 64 + p;
    const float4 pi = pts[il];
    const float sqi = pi.w;

    float d0 = 1e30f, d1 = 1e30f, d2v = 1e30f, d3 = 1e30f;
#pragma unroll 4
    for (int it = 0; it < 256; ++it) {
        const int q = (it << 2) | sub;
        const float dq = dist2(pi, sqi, pts[q]);
        d3  = __builtin_amdgcn_fmed3f(dq, d2v, d3);
        d2v = __builtin_amdgcn_fmed3f(dq, d1, d2v);
        d1  = __builtin_amdgcn_fmed3f(dq, d0, d1);
        d0  = fminf(dq, d0);
    }
    {
        float* sp = &sd[t * 4];
        sp[0] = d0; sp[1] = d1; sp[2] = d2v; sp[3] = d3;
    }
    __syncthreads();

    if (t < 64) {
        float e0 = 1e30f, e1 = 1e30f, e2 = 1e30f, e3 = 1e30f, e4 = 1e30f, e5 = 1e30f;
#pragma unroll
        for (int s = 0; s < 4; ++s) {
            const float* q4 = &sd[(t * 4 + s) * 4];
#pragma unroll
            for (int k = 0; k < 4; ++k) {
                const float d = q4[k];
                e5 = __builtin_amdgcn_fmed3f(d, e4, e5);
                e4 = __builtin_amdgcn_fmed3f(d, e3, e4);
                e3 = __builtin_amdgcn_fmed3f(d, e2, e3);
                e2 = __builtin_amdgcn_fmed3f(d, e1, e2);
                e1 = __builtin_amdgcn_fmed3f(d, e0, e1);
                e0 = fminf(d, e0);
            }
        }
        thr[t] = e5;
    }
    __syncthreads();

    const float th = thr[p];
    int cnt = 0;
#pragma unroll 4
    for (int it = 0; it < 256; ++it) {
        const int q = (it << 2) | sub;
        const float dq = dist2(pi, sqi, pts[q]);
        if (dq <= th) {
            ci[t * 8 + (cnt & 7)] = q;
            ++cnt;
        }
    }
    cn[t] = (cnt > 8) ? 8 : cnt;
    __syncthreads();

    if (t < 64) {
        const float4 pit = pts[chunk * 64 + t];
        const float sqit = pit.w;
        float e0 = 1e30f, e1 = 1e30f, e2 = 1e30f, e3 = 1e30f, e4 = 1e30f, e5 = 1e30f;
        int j0 = 0x7fffffff, j1 = 0x7fffffff, j2 = 0x7fffffff,
            j3 = 0x7fffffff, j4 = 0x7fffffff, j5 = 0x7fffffff;
#pragma unroll
        for (int s = 0; s < 4; ++s) {
            const int tid = t * 4 + s;
            const int n = cn[tid];
            for (int e = 0; e < n; ++e) {
                const int q = ci[tid * 8 + e];
                const float d = dist2(pit, sqit, pts[q]);
                if (d < e5 || (d == e5 && q < j5)) {
                    if (d < e4 || (d == e4 && q < j4)) {
                        e5 = e4; j5 = j4;
                        if (d < e3 || (d == e3 && q < j3)) {
                            e4 = e3; j4 = j3;
                            if (d < e2 || (d == e2 && q < j2)) {
                                e3 = e2; j3 = j2;
                                if (d < e1 || (d == e1 && q < j1)) {
                                    e2 = e1; j2 = j1;
                                    if (d < e0 || (d == e0 && q < j0)) {
                                        e1 = e0; j1 = j0; e0 = d; j0 = q;
                                    } else { e1 = d; j1 = q; }
                                } else { e2 = d; j2 = q; }
                            } else { e3 = d; j3 = q; }
                        } else { e4 = d; j4 = q; }
                    } else { e5 = d; j5 = q; }
                }
            }
        }
        const int gb = b * NP;
        int* op = idx + (size_t)(gb + chunk * 64 + t) * 6;
        op[0] = gb + j0; op[1] = gb + j1; op[2] = gb + j2;
        op[3] = gb + j3; op[4] = gb + j4; op[5] = gb + j5;
    }
}

// ---------------------------------------------------------------------------
// Kernel 2: layer-1 prep: U1 = b1 + pos@(W1a-W1c); Vpos = pos@(W1b+W1c).
// ---------------------------------------------------------------------------
__global__ __launch_bounds__(256) void prep1_kernel(
    const float* __restrict__ pos, const float* __restrict__ W1,
    const float* __restrict__ b1, float* __restrict__ Uout,
    float* __restrict__ Vout)
{
    const int gid = blockIdx.x * 256 + threadIdx.x;
    const int i = gid >> 6;
    const int c = gid & 63;
    const float px = pos[i * 3 + 0], py = pos[i * 3 + 1], pz = pos[i * 3 + 2];
    float u = b1[c];
    u = fmaf(px, W1[0 * 64 + c] - W1[6 * 64 + c], u);
    u = fmaf(py, W1[1 * 64 + c] - W1[7 * 64 + c], u);
    u = fmaf(pz, W1[2 * 64 + c] - W1[8 * 64 + c], u);
    Uout[(size_t)i * 64 + c] = u;
    float v =      px * (W1[3 * 64 + c] + W1[6 * 64 + c]);
    v = fmaf(py, W1[4 * 64 + c] + W1[7 * 64 + c], v);
    v = fmaf(pz, W1[5 * 64 + c] + W1[8 * 64 + c], v);
    Vout[(size_t)i * 64 + c] = v;
}

// ---------------------------------------------------------------------------
// Kernel 3: FUSED edge(N) + uv(N+1). One wave handles 16 points:
//   edge phase: TPW=16/PT tiles of relu(U[i]+V[j]) @ W2 + neighbor-max
//               -> h rows kept in wave-private LDS (fp32, row stride 68
//               floats = 272B, 16B-aligned for b128 A-frag reads).
//   uv phase:   [U'|V'] = h @ [W1n_a|W1n_b] (+/- pos@W1n_c, +b1n) -> global.
// h never touches global memory. XCD-swizzled (blockIdx%8 -> 8 graphs).
// Grid 1024 = 8 xcd-slots x 8 graphs x 16 sub-blocks (64 points/block).
// Math identical to the unfused R15 pipeline (same fp32 h, same MFMA order).
// ---------------------------------------------------------------------------
template <int PT, int KP, int KREAL>
__global__ __launch_bounds__(256) void fused_edge_uv_kernel(
    const float* __restrict__ U, const float* __restrict__ V,
    const int* __restrict__ idx,
    const float* __restrict__ W2, const float* __restrict__ b2,
    const float* __restrict__ W1n, const float* __restrict__ b1n,
    const float* __restrict__ pos,
    float* __restrict__ Uout, float* __restrict__ Vout,
    float* __restrict__ pooled_zero)
{
    __shared__ char  stag[4 * 16 * 272];
    __shared__ float hlds[4][16 * 68];
    const int t = threadIdx.x;
    const int lane = t & 63;
    const int wv = __builtin_amdgcn_readfirstlane(t >> 6);
    char* base = &stag[wv * 16 * 272];
    float* hw = &hlds[wv][0];
    const int col = lane & 15;
    const int quad = lane >> 4;
    constexpr int KSH = (KP == 8) ? 3 : 2;
    constexpr int TPW = 16 / PT;

    if (pooled_zero != nullptr && blockIdx.x == 0) {
#pragma unroll
        for (int i = 0; i < 16; ++i) pooled_zero[i * 256 + t] = 0.0f;
    }

    const int x = blockIdx.x & 7;        // XCD slot
    const int r = blockIdx.x >> 3;       // 0..127
    const int g = x * 8 + (r & 7);       // graph
    const int sb = r >> 3;               // 0..15
    const int base16 = g * NP + sb * 64 + wv * 16;   // this wave's 16 points

    // ---- W2 B-frags (edge phase) ------------------------------------------
    {
        v8s bh[4][2], bl[4][2];
#pragma unroll
        for (int nt = 0; nt < 4; ++nt) {
#pragma unroll
            for (int ks = 0; ks < 2; ++ks) {
                float w[8];
#pragma unroll
                for (int j = 0; j < 8; ++j)
                    w[j] = W2[(size_t)(ks * 32 + quad * 8 + j) * 64 + nt * 16 + col];
                pack8(w, bh[nt][ks], bl[nt][ks]);
            }
        }
        float b2v[4];
#pragma unroll
        for (int nt = 0; nt < 4; ++nt) b2v[nt] = b2[nt * 16 + col];

        for (int tt = 0; tt < TPW; ++tt) {
            const int pb = base16 + tt * PT;

            float u[PT];
#pragma unroll
            for (int p = 0; p < PT; ++p) u[p] = U[(size_t)(pb + p) * 64 + lane];

#pragma unroll
            for (int e = 0; e < 16; ++e) {
                const int p = e >> KSH;
                int k = e & (KP - 1);
                if (k >= KREAL) k = 0;
                const int j = __builtin_amdgcn_readfirstlane(idx[(size_t)(pb + p) * 6 + k]);
                float tv = u[p] + V[(size_t)j * 64 + lane];
                tv = fmaxf(tv, 0.0f);
                const unsigned int tu = __float_as_uint(tv);
                const unsigned int hi = tu & 0xffff0000u;
                const float lo = tv - __uint_as_float(hi);
                *((short*)(base + e * 272) + lane)       = (short)(hi >> 16);
                *((short*)(base + e * 272 + 128) + lane) = (short)(__float_as_uint(lo) >> 16);
            }
            __builtin_amdgcn_wave_barrier();
            __builtin_amdgcn_s_waitcnt(0xc07f);

            v8s ah[2], al[2];
#pragma unroll
            for (int ks = 0; ks < 2; ++ks) {
                ah[ks] = *(const v8s*)(base + (lane & 15) * 272 + ks * 64 + quad * 16);
                al[ks] = *(const v8s*)(base + (lane & 15) * 272 + 128 + ks * 64 + quad * 16);
            }

            f32x4 acc[4];
#pragma unroll
            for (int nt = 0; nt < 4; ++nt) acc[nt] = (f32x4){0.f, 0.f, 0.f, 0.f};
#pragma unroll
            for (int nt = 0; nt < 4; ++nt) {
#pragma unroll
                for (int ks = 0; ks < 2; ++ks) {
                    acc[nt] = __builtin_amdgcn_mfma_f32_16x16x32_bf16(ah[ks], bh[nt][ks], acc[nt], 0, 0, 0);
                    acc[nt] = __builtin_amdgcn_mfma_f32_16x16x32_bf16(ah[ks], bl[nt][ks], acc[nt], 0, 0, 0);
                    acc[nt] = __builtin_amdgcn_mfma_f32_16x16x32_bf16(al[ks], bh[nt][ks], acc[nt], 0, 0, 0);
                }
            }

            // epilogue -> wave-private LDS h rows
#pragma unroll
            for (int nt = 0; nt < 4; ++nt) {
                float m = fmaxf(fmaxf(acc[nt].x, acc[nt].y), fmaxf(acc[nt].z, acc[nt].w));
                if (KP == 4) {
                    const float z = fmaxf(m + b2v[nt], 0.0f);
                    hw[(tt * 4 + quad) * 68 + nt * 16 + col] = z;
                } else {
                    m = fmaxf(m, __shfl_xor(m, 16));
                    const float z = fmaxf(m + b2v[nt], 0.0f);
                    if ((lane & 16) == 0)
                        hw[(tt * 2 + (lane >> 5)) * 68 + nt * 16 + col] = z;
                }
            }
        }
    }
    __builtin_amdgcn_wave_barrier();
    __builtin_amdgcn_s_waitcnt(0xc07f);   // h rows visible to this wave

    // ---- uv phase: [U'|V'] = h @ [W1n_a|W1n_b] ----------------------------
    v8s ah[2], al[2];
#pragma unroll
    for (int ks = 0; ks < 2; ++ks) {
        float w[8];
        const float4 f0 = *(const float4*)(hw + col * 68 + ks * 32 + quad * 8);
        const float4 f1 = *(const float4*)(hw + col * 68 + ks * 32 + quad * 8 + 4);
        w[0] = f0.x; w[1] = f0.y; w[2] = f0.z; w[3] = f0.w;
        w[4] = f1.x; w[5] = f1.y; w[6] = f1.z; w[7] = f1.w;
        pack8(w, ah[ks], al[ks]);
    }

    float prx[4], pry[4], prz[4];
#pragma unroll
    for (int r2 = 0; r2 < 4; ++r2) {
        const int pt = base16 + quad * 4 + r2;
        prx[r2] = pos[pt * 3 + 0];
        pry[r2] = pos[pt * 3 + 1];
        prz[r2] = pos[pt * 3 + 2];
    }
    float wcx[4], wcy[4], wcz[4], b1v[4];
#pragma unroll
    for (int nt = 0; nt < 4; ++nt) {
        wcx[nt] = W1n[128 * 64 + nt * 16 + col];
        wcy[nt] = W1n[129 * 64 + nt * 16 + col];
        wcz[nt] = W1n[130 * 64 + nt * 16 + col];
        b1v[nt] = b1n[nt * 16 + col];
    }

    for (int half = 1; half >= 0; --half) {
        v8s bh[4][2], bl[4][2];
#pragma unroll
        for (int nt = 0; nt < 4; ++nt) {
#pragma unroll
            for (int ks = 0; ks < 2; ++ks) {
                float w[8];
#pragma unroll
                for (int j = 0; j < 8; ++j)
                    w[j] = W1n[(size_t)(half * 64 + ks * 32 + quad * 8 + j) * 64 + nt * 16 + col];
                pack8(w, bh[nt][ks], bl[nt][ks]);
            }
        }

        f32x4 acc[4];
#pragma unroll
        for (int nt = 0; nt < 4; ++nt) acc[nt] = (f32x4){0.f, 0.f, 0.f, 0.f};
#pragma unroll
        for (int nt = 0; nt < 4; ++nt) {
#pragma unroll
            for (int ks = 0; ks < 2; ++ks) {
                acc[nt] = __builtin_amdgcn_mfma_f32_16x16x32_bf16(ah[ks], bh[nt][ks], acc[nt], 0, 0, 0);
                acc[nt] = __builtin_amdgcn_mfma_f32_16x16x32_bf16(ah[ks], bl[nt][ks], acc[nt], 0, 0, 0);
                acc[nt] = __builtin_amdgcn_mfma_f32_16x16x32_bf16(al[ks], bh[nt][ks], acc[nt], 0, 0, 0);
            }
        }

        float* outp = half ? Vout : Uout;
#pragma unroll
        for (int nt = 0; nt < 4; ++nt) {
            const float* a = (const float*)&acc[nt];
#pragma unroll
            for (int r2 = 0; r2 < 4; ++r2) {
                float dotp = fmaf(prz[r2], wcz[nt], fmaf(pry[r2], wcy[nt], prx[r2] * wcx[nt]));
                float val = half ? (a[r2] + dotp) : (a[r2] + b1v[nt] - dotp);
                outp[(size_t)(base16 + quad * 4 + r2) * 64 + nt * 16 + col] = val;
            }
        }
    }
}

// ---------------------------------------------------------------------------
// Kernel 4: final edge layer with atomic max-pool epilogue (R15 form,
// XCD-swizzled). Grid 2048 = 8 slots x 8 graphs x 32 sub-blocks.
// ---------------------------------------------------------------------------
template <int PT, int KP, int KREAL, int TPW>
__global__ __launch_bounds__(256) void edge3_mfma_kernel(
    const float* __restrict__ U, const float* __restrict__ V,
    const int* __restrict__ idx,
    const float* __restrict__ W2, const float* __restrict__ b2,
    float* __restrict__ outp)
{
    __shared__ char ldsbuf[4 * 16 * 272];
    const int t = threadIdx.x;
    const int lane = t & 63;
    const int wv = __builtin_amdgcn_readfirstlane(t >> 6);
    char* base = &ldsbuf[wv * 16 * 272];
    const int col = lane & 15;
    const int quad = lane >> 4;
    constexpr int KSH = (KP == 8) ? 3 : 2;

    v8s bh[4][2], bl[4][2];
#pragma unroll
    for (int nt = 0; nt < 4; ++nt) {
#pragma unroll
        for (int ks = 0; ks < 2; ++ks) {
            float w[8];
#pragma unroll
            for (int j = 0; j < 8; ++j)
                w[j] = W2[(size_t)(ks * 32 + quad * 8 + j) * 64 + nt * 16 + col];
            pack8(w, bh[nt][ks], bl[nt][ks]);
        }
    }
    float b2v[4];
#pragma unroll
    for (int nt = 0; nt < 4; ++nt) b2v[nt] = b2[nt * 16 + col];

    const int x = blockIdx.x & 7;
    const int r = blockIdx.x >> 3;
    const int g = x * 8 + (r & 7);
    const int sb = r >> 3;

    for (int tt = 0; tt < TPW; ++tt) {
        const int tig = (sb * 4 + wv) * TPW + tt;
        const int pb = g * NP + tig * PT;

        float u[PT];
#pragma unroll
        for (int p = 0; p < PT; ++p) u[p] = U[(size_t)(pb + p) * 64 + lane];

#pragma unroll
        for (int e = 0; e < 16; ++e) {
            const int p = e >> KSH;
            int k = e & (KP - 1);
            if (k >= KREAL) k = 0;
            const int j = __builtin_amdgcn_readfirstlane(idx[(size_t)(pb + p) * 6 + k]);
            float tv = u[p] + V[(size_t)j * 64 + lane];
            tv = fmaxf(tv, 0.0f);
            const unsigned int tu = __float_as_uint(tv);
            const unsigned int hi = tu & 0xffff0000u;
            const float lo = tv - __uint_as_float(hi);
            *((short*)(base + e * 272) + lane)       = (short)(hi >> 16);
            *((short*)(base + e * 272 + 128) + lane) = (short)(__float_as_uint(lo) >> 16);
        }
        __builtin_amdgcn_wave_barrier();
        __builtin_amdgcn_s_waitcnt(0xc07f);

        v8s ah[2], al[2];
#pragma unroll
        for (int ks = 0; ks < 2; ++ks) {
            ah[ks] = *(const v8s*)(base + (lane & 15) * 272 + ks * 64 + quad * 16);
            al[ks] = *(const v8s*)(base + (lane & 15) * 272 + 128 + ks * 64 + quad * 16);
        }

        f32x4 acc[4];
#pragma unroll
        for (int nt = 0; nt < 4; ++nt) acc[nt] = (f32x4){0.f, 0.f, 0.f, 0.f};
#pragma unroll
        for (int nt = 0; nt < 4; ++nt) {
#pragma unroll
            for (int ks = 0; ks < 2; ++ks) {
                acc[nt] = __builtin_amdgcn_mfma_f32_16x16x32_bf16(ah[ks], bh[nt][ks], acc[nt], 0, 0, 0);
                acc[nt] = __builtin_amdgcn_mfma_f32_16x16x32_bf16(ah[ks], bl[nt][ks], acc[nt], 0, 0, 0);
                acc[nt] = __builtin_amdgcn_mfma_f32_16x16x32_bf16(al[ks], bh[nt][ks], acc[nt], 0, 0, 0);
            }
        }

#pragma unroll
        for (int nt = 0; nt < 4; ++nt) {
            float m = fmaxf(fmaxf(acc[nt].x, acc[nt].y), fmaxf(acc[nt].z, acc[nt].w));
            const float z0 = fmaxf(m + b2v[nt], 0.0f);
            float zm = fmaxf(z0, __shfl_xor(z0, 16));
            zm = fmaxf(zm, __shfl_xor(zm, 32));
            if (quad == 0) {
                atomicMax((unsigned int*)(outp + (size_t)g * 64 + nt * 16 + col),
                          __float_as_uint(zm));
            }
        }
    }
}

// ---------------------------------------------------------------------------
// Kernel 5: final 64->6 regression from pooled. 6 blocks x 64 threads.
// ---------------------------------------------------------------------------
__global__ __launch_bounds__(64) void reg_kernel(
    const float* __restrict__ pooled, const float* __restrict__ regW,
    const float* __restrict__ regb, float* __restrict__ out)
{
    const int t = blockIdx.x * 64 + threadIdx.x;
    const int b = t / 6;
    const int o = t - b * 6;
    if (t < NB * 6) {
        float z = regb[o];
        const float* pb = pooled + (size_t)b * 64;
        for (int c = 0; c < 64; ++c) z = fmaf(pb[c], regW[c * 6 + o], z);
        out[b * 6 + o] = z;
    }
}

// ---------------------------------------------------------------------------
extern "C" void kernel_launch(void* const* d_in, const int* in_sizes, int n_in,
                              void* d_out, int out_size, void* d_ws, size_t ws_size,
                              hipStream_t stream)
{
    (void)in_sizes; (void)n_in; (void)out_size; (void)ws_size;
    const float* pos   = (const float*)d_in[1];
    const float* c1W1  = (const float*)d_in[3];
    const float* c1b1  = (const float*)d_in[4];
    const float* c1W2  = (const float*)d_in[5];
    const float* c1b2  = (const float*)d_in[6];
    const float* c2W1  = (const float*)d_in[7];
    const float* c2b1  = (const float*)d_in[8];
    const float* c2W2  = (const float*)d_in[9];
    const float* c2b2  = (const float*)d_in[10];
    const float* c3W1  = (const float*)d_in[11];
    const float* c3b1  = (const float*)d_in[12];
    const float* c3W2  = (const float*)d_in[13];
    const float* c3b2  = (const float*)d_in[14];
    const float* regW  = (const float*)d_in[15];
    const float* regb  = (const float*)d_in[16];
    float* out = (float*)d_out;

    // workspace: idx | A | C | D | E | pooled  (A,C,D,E are 65536x64 fp32)
    char* ws = (char*)d_ws;
    int*   idx = (int*)ws;                                    // 1.5 MB
    float* A = (float*)(ws + 1572864);
    float* C = (float*)(ws + 1572864 + 1 * 16777216);
    float* D = (float*)(ws + 1572864 + 2 * 16777216);
    float* E = (float*)(ws + 1572864 + 3 * 16777216);
    float* pooled = (float*)(ws + 1572864 + 4 * 16777216);    // 16 KB

    // prep: U1 -> D, Vpos -> C ; kNN single launch
    prep1_kernel<<<NPTS * 64 / 256, 256, 0, stream>>>(pos, c1W1, c1b1, D, C);
    knn6_kernel<<<NB * 16, 256, 0, stream>>>(pos, idx);

    // fused layer1-edge + layer2-uv: reads (D=U1, C=Vpos) -> U2->A, V2->E
    fused_edge_uv_kernel<2, 8, 6><<<1024, 256, 0, stream>>>(
        D, C, idx, c1W2, c1b2, c2W1, c2b1, pos, A, E, nullptr);

    // fused layer2-edge + layer3-uv: reads (A=U2, E=V2) -> U3->D, V3->C
    // (block 0 zeroes pooled)
    fused_edge_uv_kernel<4, 4, 4><<<1024, 256, 0, stream>>>(
        A, E, idx, c2W2, c2b2, c3W1, c3b1, pos, D, C, pooled);

    // layer3 edge -> atomic max into pooled
    edge3_mfma_kernel<4, 4, 3, 2><<<2048, 256, 0, stream>>>(
        D, C, idx, c3W2, c3b2, pooled);

    // final regression
    reg_kernel<<<6, 64, 0, stream>>>(pooled, regW, regb, out);
}